// Round 1
// baseline (940.876 us; speedup 1.0000x reference)
//
#include <hip/hip_runtime.h>

// SSIM (32,3,512,512) fp32, separable 11x11 Gaussian, sqrt-free rational form.
// v8 = v7 + multi-wave workgroups to beat the per-CU workgroup-slot cap.
//   v7 post-mortem: waves_per_eu(2,6) did NOT raise occupancy (28.5%->30.2%).
//   VGPR (76 -> 6 waves/SIMD ok) and LDS (24*6656=159.7KB fits) both allow
//   24 waves/CU, yet only ~9.7 waves/CU average were resident. Remaining
//   candidate: HW workgroup-slot limit (~16 WGs/CU) -- 24 single-wave WGs
//   demanded, 16 resident + ragged 8-WG drain ==> time-avg ~30%. Matches.
//   Fix: pack 4 independent waves (4 tiles) per 256-thread workgroup.
//   1536 WGs = 6 WGs/CU (LDS 4*6512=26048B, 6*26048=152.6KB fits 160KiB)
//   x 4 waves = 24 waves/CU = 6/SIMD, whole grid co-resident, 6 WG slots.
//   No inter-wave data sharing -> __syncthreads() replaced by wave-local
//   "s_waitcnt lgkmcnt(0)" fence (v3 lesson: the waitcnt is the required
//   half; s_barrier was a single-wave no-op and would now lockstep 4 waves).
//   Predicted: Occupancy >=65%, VALUBusy >=92%, dur 210 -> ~75-100us
//   (VALU floor ~58us).
// Carried lessons: waves_per_eu min caps regs / max stops spill-chasing (v2,
// v5, v6); cross-lane LDS visibility needs waitcnt + compiler fence (v3);
// readfirstlane is int(int), bit-cast floats (v4); 256-bin atomic fan-out (v7).

#define IMG_H 512
#define IMG_W 512
#define N_IMGS 96                    // 32 batch * 3 channels
#define WAVE_W 64                    // output cols per wave
#define STRIPE 64                    // output rows per wave
#define HALO 5
#define KW 11
#define IN_COLS (WAVE_W + 2*HALO)    // 74
#define N_ROWT (IMG_H / STRIPE)      // 8
#define N_COLT (IMG_W / WAVE_W)      // 8
#define N_TILES (N_IMGS * N_ROWT * N_COLT)   // 6144 tiles, one per wave
#define WPB 4                        // waves (tiles) per workgroup
#define N_BLOCKS (N_TILES / WPB)     // 1536 = 6 WGs/CU exactly, all resident
#define T_MAX 77                     // 7*11 steps; t=74..76 are drain no-ops
#define NBINS 256
#define TOTAL_PIX (32.0f * 3.0f * 512.0f * 512.0f)

__global__ __launch_bounds__(64 * WPB)
__attribute__((amdgpu_waves_per_eu(6, 8)))
void ssim_main(
    const float* __restrict__ img1, const float* __restrict__ img2,
    const float* __restrict__ window, float* __restrict__ bins)
{
    // Per-wave private ring regions; no cross-wave sharing.
    __shared__ float2 ring_all[WPB][KW][IN_COLS];   // 4 x 6512 B = 26048 B

    const int lane = threadIdx.x & 63;     // one output column per lane
    const int wv   = threadIdx.x >> 6;     // wave id within WG -> tile id
    float2 (* __restrict__ ring)[IN_COLS] = ring_all[wv];

    // 1D gaussian, wave-uniform (SGPRs): g[k] = w[5][k] / sqrt(w[5][5]).
    float g[KW];
    {
        const float inv = rsqrtf(window[5*KW + 5]);
        #pragma unroll
        for (int k = 0; k < KW; ++k)
            g[k] = __int_as_float(
                __builtin_amdgcn_readfirstlane(
                    __float_as_int(window[5*KW + k] * inv)));
    }

    const int b   = blockIdx.x * WPB + wv; // tile index 0..6143
    const int img = b >> 6;                // 8x8 tiles per image
    const int rem = b & 63;
    const int ty  = rem >> 3;              // 0..7 row stripe
    const int tx  = rem & 7;               // 0..7 col stripe
    const int r0  = ty * STRIPE;
    const int x0  = tx * WAVE_W;

    const float* __restrict__ p1 = img1 + (size_t)img * (IMG_H * IMG_W);
    const float* __restrict__ p2 = img2 + (size_t)img * (IMG_H * IMG_W);

    // Staging columns: lane covers ring col lane (gx = x0-5+lane); lanes
    // 0..9 also cover ring col lane+64.
    const int  gx1  = x0 - HALO + lane;
    const bool c1ok = (unsigned)gx1 < IMG_W;
    const bool tail = lane < (IN_COLS - WAVE_W);    // lanes 0..9
    const int  gx2  = gx1 + WAVE_W;
    const bool c2ok = tail && ((unsigned)gx2 < IMG_W);

    // h-value register ring (5 signals x 11 slots) -- stays in VGPRs.
    float r_h1[KW], r_h2[KW], r_h11[KW], r_h22[KW], r_h12[KW];
    #pragma unroll
    for (int i = 0; i < KW; ++i) {
        r_h1[i] = 0.f; r_h2[i] = 0.f; r_h11[i] = 0.f; r_h22[i] = 0.f; r_h12[i] = 0.f;
    }

    const float C1 = 1e-4f;   // (0.01*1.0)^2
    const float C2 = 9e-4f;   // (0.03*1.0)^2
    float sum = 0.f;

    // Prologue: load input row t=0 (gy = r0-5) into staging registers.
    float sa = 0.f, sb = 0.f, sa2 = 0.f, sb2 = 0.f;
    {
        const int gy = r0 - HALO;
        if ((unsigned)gy < IMG_H) {
            const int base = gy * IMG_W;
            if (c1ok) { sa  = p1[base + gx1]; sb  = p2[base + gx1]; }
            if (c2ok) { sa2 = p1[base + gx2]; sb2 = p2[base + gx2]; }
        }
    }

    #pragma unroll 1
    for (int tb = 0; tb < T_MAX; tb += KW) {
        #pragma unroll
        for (int u = 0; u < KW; ++u) {       // t % 11 == u, static ring slots
            const int t = tb + u;

            // 1) Publish row t into this wave's ring slot u.
            ring[u][lane] = make_float2(sa, sb);
            if (tail) ring[u][lane + WAVE_W] = make_float2(sa2, sb2);

            // 2) Wave-local cross-lane visibility: wait for the ds_writes
            //    and stop the compiler from hoisting the ds_reads above.
            //    (No s_barrier: waves in this WG are fully independent.)
            asm volatile("s_waitcnt lgkmcnt(0)" ::: "memory");

            // 3) Issue global loads for row t+1 (waited at next ds_write).
            {
                const int gy = r0 - HALO + t + 1;
                sa = 0.f; sb = 0.f; sa2 = 0.f; sb2 = 0.f;
                if ((unsigned)gy < IMG_H) {
                    const int base = gy * IMG_W;
                    if (c1ok) { sa  = p1[base + gx1]; sb  = p2[base + gx1]; }
                    if (c2ok) { sa2 = p1[base + gx2]; sb2 = p2[base + gx2]; }
                }
            }

            // 4) Horizontal 11-tap conv at col x0+lane from ring slot u.
            float h1 = 0.f, h2 = 0.f, h11 = 0.f, h22 = 0.f, h12 = 0.f;
            #pragma unroll
            for (int k = 0; k < KW; ++k) {
                const float2 v = ring[u][lane + k];
                const float t1 = g[k] * v.x;
                const float t2 = g[k] * v.y;
                h1  += t1;
                h2  += t2;
                h11 += t1 * v.x;
                h22 += t2 * v.y;
                h12 += t1 * v.y;
            }
            r_h1[u] = h1; r_h2[u] = h2; r_h11[u] = h11; r_h22[u] = h22; r_h12[u] = h12;

            // 5) Vertical gather + SSIM for output row r0 + t - 10
            //    (uniform branch: t depends only on tb/u).
            if (t >= 2*HALO && t < 2*HALO + STRIPE) {
                float mu1 = 0.f, mu2 = 0.f, e11 = 0.f, e22 = 0.f, e12 = 0.f;
                #pragma unroll
                for (int m = 0; m < KW; ++m) {
                    const int slot = (u + 1 + m) % KW;  // compile-time index
                    mu1 += g[m] * r_h1[slot];
                    mu2 += g[m] * r_h2[slot];
                    e11 += g[m] * r_h11[slot];
                    e22 += g[m] * r_h22[slot];
                    e12 += g[m] * r_h12[slot];
                }
                const float mu1s = mu1 * mu1, mu2s = mu2 * mu2, mu12 = mu1 * mu2;
                const float s1  = fmaxf(e11 - mu1s, 0.f);
                const float s2  = fmaxf(e22 - mu2s, 0.f);
                const float s12 = e12 - mu12;
                const float num = (2.f * mu12 + C1) * (2.f * s12 + C2);
                const float den = (mu1s + mu2s + C1) * (s1 + s2 + C2);
                sum += num * __builtin_amdgcn_rcpf(den);
            }
        }
    }

    // Per-wave reduction -> one atomicAdd per wave, fanned over 256 bins.
    #pragma unroll
    for (int off = 32; off > 0; off >>= 1)
        sum += __shfl_down(sum, off, 64);
    if (lane == 0)
        atomicAdd(&bins[b & (NBINS - 1)], sum);
}

__global__ __launch_bounds__(64) void ssim_final(
    const float* __restrict__ bins, float* __restrict__ out)
{
    const int tid = threadIdx.x;
    float s = 0.f;
    #pragma unroll
    for (int i = 0; i < NBINS / 64; ++i) s += bins[tid + i * 64];
    #pragma unroll
    for (int off = 32; off > 0; off >>= 1)
        s += __shfl_down(s, off, 64);
    if (tid == 0) out[0] = s * (1.0f / TOTAL_PIX);
}

extern "C" void kernel_launch(void* const* d_in, const int* in_sizes, int n_in,
                              void* d_out, int out_size, void* d_ws, size_t ws_size,
                              hipStream_t stream) {
    const float* img1   = (const float*)d_in[0];
    const float* img2   = (const float*)d_in[1];
    const float* window = (const float*)d_in[2];
    float* bins = (float*)d_ws;
    float* out  = (float*)d_out;

    hipMemsetAsync(bins, 0, NBINS * sizeof(float), stream);
    ssim_main<<<N_BLOCKS, 64 * WPB, 0, stream>>>(img1, img2, window, bins);
    ssim_final<<<1, 64, 0, stream>>>(bins, out);
}

// Round 2
// 321.598 us; speedup vs baseline: 2.9256x; 2.9256x over previous
//
#include <hip/hip_runtime.h>

// SSIM (32,3,512,512) fp32, separable 11x11 Gaussian, sqrt-free rational form.
// v9 = v8 structure (4 waves/WG, confirmed 69% occupancy) minus the spill.
//   v8 post-mortem: waves_per_eu(6,8) made the allocator target ~12 waves/EU
//   (VGPR 40!) and spill the 55-reg h-ring -> 1.25GB scratch writes, 810us.
//   BUT warm occupancy hit 69% (~24 waves/CU = LDS max) -> multi-wave WGs
//   beat the v7 cap. Keep the structure, fix the registers WITHOUT coercion:
//   1) Drop waves_per_eu entirely (v2/v5/v6/v8 lesson: min-coercion spills).
//   2) The 11-slot LDS input ring was vestigial -- horizontal conv only reads
//      the slot written the same step; vertical history is the VGPR h-ring.
//      2-slot row buffer: 6512 -> 1216 B/wave.
//   3) Spend the freed LDS to offload the h12 ring (11 VGPRs) to LDS
//      (2816 B/wave, +12 LDS ops/step on an underused pipe): natural VGPR
//      ~76 -> ~62-66, under the 64-reg occupancy quantum (m69: waves halve
//      at 64/128/256). HW grants 6-8 waves/SIMD on its own.
//   Per-WG LDS 16128 B -> LDS allows 10 WGs/CU; grid needs 6 WGs/CU
//   (1536 x 4 waves = 24/CU) -> whole grid resident, zero drain.
//   Predicted: VGPR<=68, WRITE back to ~0.2KB, occupancy ~75%, main ~75-115us.
// Carried lessons: no waves_per_eu coercion (v2,v5,v6,v8); cross-lane LDS
// visibility needs waitcnt+fence (v3); readfirstlane is int(int), bit-cast
// floats (v4); 256-bin atomic fan-out (v7); 4-wave WGs for residency (v8).

#define IMG_H 512
#define IMG_W 512
#define N_IMGS 96                    // 32 batch * 3 channels
#define WAVE_W 64                    // output cols per wave
#define STRIPE 64                    // output rows per wave
#define HALO 5
#define KW 11
#define IN_COLS (WAVE_W + 2*HALO)    // 74
#define N_ROWT (IMG_H / STRIPE)      // 8
#define N_COLT (IMG_W / WAVE_W)      // 8
#define N_TILES (N_IMGS * N_ROWT * N_COLT)   // 6144 tiles, one per wave
#define WPB 4                        // waves (tiles) per workgroup
#define N_BLOCKS (N_TILES / WPB)     // 1536 = 6 WGs/CU, all resident
#define T_MAX 77                     // 7*11 steps; t=74..76 are drain no-ops
#define NBINS 256
#define TOTAL_PIX (32.0f * 3.0f * 512.0f * 512.0f)

__global__ __launch_bounds__(64 * WPB)
void ssim_main(
    const float* __restrict__ img1, const float* __restrict__ img2,
    const float* __restrict__ window, float* __restrict__ bins)
{
    // Per-wave private LDS; no cross-wave sharing.
    __shared__ float2 rowbuf_all[WPB][2][IN_COLS + 2];  // 2-slot row buf, 1216 B/wave
    __shared__ float  h12_all[WPB][KW][WAVE_W];         // h12 ring, 2816 B/wave

    const int lane = threadIdx.x & 63;     // one output column per lane
    const int wv   = threadIdx.x >> 6;     // wave id within WG -> tile id
    float2 (* __restrict__ rowbuf)[IN_COLS + 2] = rowbuf_all[wv];
    float  (* __restrict__ h12r)[WAVE_W]        = h12_all[wv];

    // 1D gaussian, wave-uniform (SGPRs): g[k] = w[5][k] / sqrt(w[5][5]).
    float g[KW];
    {
        const float inv = rsqrtf(window[5*KW + 5]);
        #pragma unroll
        for (int k = 0; k < KW; ++k)
            g[k] = __int_as_float(
                __builtin_amdgcn_readfirstlane(
                    __float_as_int(window[5*KW + k] * inv)));
    }

    const int b   = blockIdx.x * WPB + wv; // tile index 0..6143
    const int img = b >> 6;                // 8x8 tiles per image
    const int rem = b & 63;
    const int ty  = rem >> 3;              // 0..7 row stripe
    const int tx  = rem & 7;               // 0..7 col stripe
    const int r0  = ty * STRIPE;
    const int x0  = tx * WAVE_W;

    const float* __restrict__ p1 = img1 + (size_t)img * (IMG_H * IMG_W);
    const float* __restrict__ p2 = img2 + (size_t)img * (IMG_H * IMG_W);

    // Staging columns: lane covers row-buffer col lane (gx = x0-5+lane);
    // lanes 0..9 also cover col lane+64.
    const int  gx1  = x0 - HALO + lane;
    const bool c1ok = (unsigned)gx1 < IMG_W;
    const bool tail = lane < (IN_COLS - WAVE_W);    // lanes 0..9
    const int  gx2  = gx1 + WAVE_W;
    const bool c2ok = tail && ((unsigned)gx2 < IMG_W);

    // h-value register ring: 4 signals x 11 slots in VGPRs (h12 lives in LDS).
    float r_h1[KW], r_h2[KW], r_h11[KW], r_h22[KW];
    #pragma unroll
    for (int i = 0; i < KW; ++i) {
        r_h1[i] = 0.f; r_h2[i] = 0.f; r_h11[i] = 0.f; r_h22[i] = 0.f;
    }

    const float C1 = 1e-4f;   // (0.01*1.0)^2
    const float C2 = 9e-4f;   // (0.03*1.0)^2
    float sum = 0.f;

    // Prologue: load input row t=0 (gy = r0-5) into staging registers.
    float sa = 0.f, sb = 0.f, sa2 = 0.f, sb2 = 0.f;
    {
        const int gy = r0 - HALO;
        if ((unsigned)gy < IMG_H) {
            const int base = gy * IMG_W;
            if (c1ok) { sa  = p1[base + gx1]; sb  = p2[base + gx1]; }
            if (c2ok) { sa2 = p1[base + gx2]; sb2 = p2[base + gx2]; }
        }
    }

    #pragma unroll 1
    for (int tb = 0; tb < T_MAX; tb += KW) {
        #pragma unroll
        for (int u = 0; u < KW; ++u) {       // t % 11 == u, static slots
            const int t = tb + u;

            // 1) Publish row t into row-buffer slot (u&1).
            rowbuf[u & 1][lane] = make_float2(sa, sb);
            if (tail) rowbuf[u & 1][lane + WAVE_W] = make_float2(sa2, sb2);

            // 2) Wave-local cross-lane visibility: wait for the ds_writes and
            //    stop the compiler hoisting the ds_reads above them.
            //    (No s_barrier: waves in this WG are fully independent.)
            asm volatile("s_waitcnt lgkmcnt(0)" ::: "memory");

            // 3) Issue global loads for row t+1 (consumed at next publish).
            {
                const int gy = r0 - HALO + t + 1;
                sa = 0.f; sb = 0.f; sa2 = 0.f; sb2 = 0.f;
                if ((unsigned)gy < IMG_H) {
                    const int base = gy * IMG_W;
                    if (c1ok) { sa  = p1[base + gx1]; sb  = p2[base + gx1]; }
                    if (c2ok) { sa2 = p1[base + gx2]; sb2 = p2[base + gx2]; }
                }
            }

            // 4) Horizontal 11-tap conv at col x0+lane from the row buffer.
            float h1 = 0.f, h2 = 0.f, h11 = 0.f, h22 = 0.f, h12 = 0.f;
            #pragma unroll
            for (int k = 0; k < KW; ++k) {
                const float2 v = rowbuf[u & 1][lane + k];
                const float t1 = g[k] * v.x;
                const float t2 = g[k] * v.y;
                h1  += t1;
                h2  += t2;
                h11 += t1 * v.x;
                h22 += t2 * v.y;
                h12 += t1 * v.y;
            }
            r_h1[u] = h1; r_h2[u] = h2; r_h11[u] = h11; r_h22[u] = h22;
            h12r[u][lane] = h12;   // h12 ring slot u lives in LDS

            // 5) Vertical gather + SSIM for output row r0 + t - 10
            //    (uniform branch: t depends only on tb/u).
            if (t >= 2*HALO && t < 2*HALO + STRIPE) {
                float mu1 = 0.f, mu2 = 0.f, e11 = 0.f, e22 = 0.f, e12 = 0.f;
                #pragma unroll
                for (int m = 0; m < KW; ++m) {
                    const int slot = (u + 1 + m) % KW;  // compile-time index
                    mu1 += g[m] * r_h1[slot];
                    mu2 += g[m] * r_h2[slot];
                    e11 += g[m] * r_h11[slot];
                    e22 += g[m] * r_h22[slot];
                    e12 += g[m] * h12r[slot][lane];     // ds_read_b32, imm offset
                }
                const float mu1s = mu1 * mu1, mu2s = mu2 * mu2, mu12 = mu1 * mu2;
                const float s1  = fmaxf(e11 - mu1s, 0.f);
                const float s2  = fmaxf(e22 - mu2s, 0.f);
                const float s12 = e12 - mu12;
                const float num = (2.f * mu12 + C1) * (2.f * s12 + C2);
                const float den = (mu1s + mu2s + C1) * (s1 + s2 + C2);
                sum += num * __builtin_amdgcn_rcpf(den);
            }
        }
    }

    // Per-wave reduction -> one atomicAdd per wave, fanned over 256 bins.
    #pragma unroll
    for (int off = 32; off > 0; off >>= 1)
        sum += __shfl_down(sum, off, 64);
    if (lane == 0)
        atomicAdd(&bins[b & (NBINS - 1)], sum);
}

__global__ __launch_bounds__(64) void ssim_final(
    const float* __restrict__ bins, float* __restrict__ out)
{
    const int tid = threadIdx.x;
    float s = 0.f;
    #pragma unroll
    for (int i = 0; i < NBINS / 64; ++i) s += bins[tid + i * 64];
    #pragma unroll
    for (int off = 32; off > 0; off >>= 1)
        s += __shfl_down(s, off, 64);
    if (tid == 0) out[0] = s * (1.0f / TOTAL_PIX);
}

extern "C" void kernel_launch(void* const* d_in, const int* in_sizes, int n_in,
                              void* d_out, int out_size, void* d_ws, size_t ws_size,
                              hipStream_t stream) {
    const float* img1   = (const float*)d_in[0];
    const float* img2   = (const float*)d_in[1];
    const float* window = (const float*)d_in[2];
    float* bins = (float*)d_ws;
    float* out  = (float*)d_out;

    hipMemsetAsync(bins, 0, NBINS * sizeof(float), stream);
    ssim_main<<<N_BLOCKS, 64 * WPB, 0, stream>>>(img1, img2, window, bins);
    ssim_final<<<1, 64, 0, stream>>>(bins, out);
}